// Round 12
// baseline (51.898 us; speedup 1.0000x reference)
//
#include <hip/hip_runtime.h>

#define NF 13          // y = [1, x1..x12]
#define NEXP 454       // unique monomials
#define NROWS 65536
#define BN_EPS 1e-5f
#define SBLK 1024              // stats blocks (4 blocks/CU, 16 waves/CU)
#define SROWS (NROWS / SBLK)   // 64 rows per stats block
#define PARTW 908              // per-block partial row: [454 sums | 454 sumsqs]
#define SPAD (SROWS + 4)       // padded column stride: 68 words, 16B-aligned
#define WROWS 32               // rows per write block (2048 blocks, 8/CU)
#define WPAD (WROWS + 4)       // 36 words
#define FIN_FPB 32             // features per finalize block

// Decode feature index j (0..453) -> nondecreasing triple (i0<=i1<=i2),
// lexicographic order over (i0,i1,i2), skipping (0,0,0).
__device__ __forceinline__ void decode_triple(int j, int& i0, int& i1, int& i2) {
    int g = j + 1;
    i0 = 0;
    for (;;) {
        int m = NF - i0;
        int c = m * (m + 1) / 2;
        if (g < c) break;
        g -= c; ++i0;
    }
    i1 = i0;
    for (;;) {
        int m = NF - i1;
        if (g < m) break;
        g -= m; ++i1;
    }
    i2 = i1 + g;
}

// ---------------- Pass 1: per-block partial sum / sumsq (no atomics) --------
// R9 structure (proven best); only SBLK/SROWS changed: 1024 blocks x 64 rows
// -> 4 blocks/CU for latency hiding. Per-CU LDS work invariant.
__global__ __launch_bounds__(256) void stats_kernel(const float* __restrict__ x,
                                                    float* __restrict__ part) {
    __shared__ float yc[NF][SPAD];
    const int tid = threadIdx.x;
    const int row0 = blockIdx.x * SROWS;

    for (int idx = tid; idx < SROWS * 12; idx += 256) {
        int r = idx / 12, c = idx - r * 12;
        yc[c + 1][r] = x[(size_t)row0 * 12 + idx];
    }
    for (int r = tid; r < SROWS; r += 256) yc[0][r] = 1.0f;
    __syncthreads();

    const int j0 = tid;
    const int j1 = tid + 256;
    const bool has1 = (j1 < NEXP);
    int a0, a1, a2, b0 = 0, b1 = 0, b2 = 0;
    decode_triple(j0, a0, a1, a2);
    if (has1) decode_triple(j1, b0, b1, b2);

    float s0 = 0.f, q0 = 0.f, s1 = 0.f, q1 = 0.f;
    for (int r = 0; r < SROWS; r += 4) {
        float4 va = *reinterpret_cast<const float4*>(&yc[a0][r]);
        float4 vb = *reinterpret_cast<const float4*>(&yc[a1][r]);
        float4 vc = *reinterpret_cast<const float4*>(&yc[a2][r]);
        float f;
        f = va.x * vb.x * vc.x; s0 += f; q0 += f * f;
        f = va.y * vb.y * vc.y; s0 += f; q0 += f * f;
        f = va.z * vb.z * vc.z; s0 += f; q0 += f * f;
        f = va.w * vb.w * vc.w; s0 += f; q0 += f * f;
        if (has1) {
            float4 wa = *reinterpret_cast<const float4*>(&yc[b0][r]);
            float4 wb = *reinterpret_cast<const float4*>(&yc[b1][r]);
            float4 wc = *reinterpret_cast<const float4*>(&yc[b2][r]);
            f = wa.x * wb.x * wc.x; s1 += f; q1 += f * f;
            f = wa.y * wb.y * wc.y; s1 += f; q1 += f * f;
            f = wa.z * wb.z * wc.z; s1 += f; q1 += f * f;
            f = wa.w * wb.w * wc.w; s1 += f; q1 += f * f;
        }
    }
    float* p = part + (size_t)blockIdx.x * PARTW;
    p[j0] = s0;
    p[NEXP + j0] = q0;
    if (has1) {
        p[j1] = s1;
        p[NEXP + j1] = q1;
    }
}

// ---------------- Pass 2: reduce partials, fold BN into scale/shift ---------
__global__ __launch_bounds__(256) void finalize_kernel(const float* __restrict__ part,
                                                       const float* __restrict__ w,
                                                       const float* __restrict__ b,
                                                       float* __restrict__ ss) {
    __shared__ float reds[8][FIN_FPB];
    __shared__ float redq[8][FIN_FPB];
    const int fl = threadIdx.x & 31;
    const int k  = threadIdx.x >> 5;              // slice 0..7
    const int f  = blockIdx.x * FIN_FPB + fl;
    float s = 0.f, q = 0.f;
    if (f < NEXP) {
        #pragma unroll 4
        for (int i = 0; i < SBLK / 8; ++i) {
            const float* p = part + (size_t)(k * (SBLK / 8) + i) * PARTW;
            s += p[f];
            q += p[NEXP + f];
        }
    }
    reds[k][fl] = s;
    redq[k][fl] = q;
    __syncthreads();
    if (threadIdx.x < FIN_FPB && f < NEXP) {
        float ts = 0.f, tq = 0.f;
        #pragma unroll
        for (int kk = 0; kk < 8; ++kk) { ts += reds[kk][fl]; tq += redq[kk][fl]; }
        const float inv_n = 1.0f / (float)NROWS;
        float mean = ts * inv_n;
        float var  = tq * inv_n - mean * mean;
        float scale = rsqrtf(var + BN_EPS) * w[f];
        ss[f] = scale;
        ss[NEXP + f] = b[f] - mean * scale;
    }
}

// ---------------- Pass 3: recompute feats, apply affine, store --------------
// Thread t<227 owns FLAT features (2t, 2t+1): always-even index -> aligned
// float2 (dwordx2) stores, 512B contiguous per wave-instruction.
__global__ __launch_bounds__(256) void write_kernel(const float* __restrict__ x,
                                                    const float* __restrict__ ss,
                                                    float* __restrict__ out) {
    __shared__ float yc[NF][WPAD];
    const int tid = threadIdx.x;
    const int row0 = blockIdx.x * WROWS;

    for (int idx = tid; idx < WROWS * 12; idx += 256) {
        int r = idx / 12, c = idx - r * 12;
        yc[c + 1][r] = x[(size_t)row0 * 12 + idx];
    }
    for (int r = tid; r < WROWS; r += 256) yc[0][r] = 1.0f;

    const bool act = tid < NEXP / 2;     // 227 active threads
    const int j0 = 2 * tid;
    int a0 = 0, a1 = 0, a2 = 0, b0 = 0, b1 = 0, b2 = 0;
    float2 sc = {0.f, 0.f}, sh = {0.f, 0.f};
    if (act) {
        decode_triple(j0, a0, a1, a2);
        decode_triple(j0 + 1, b0, b1, b2);
        sc = *reinterpret_cast<const float2*>(&ss[j0]);          // even idx
        sh = *reinterpret_cast<const float2*>(&ss[NEXP + j0]);   // even idx
    }
    __syncthreads();

    if (act) {
        for (int r = 0; r < WROWS; r += 4) {
            float4 va = *reinterpret_cast<const float4*>(&yc[a0][r]);
            float4 vb = *reinterpret_cast<const float4*>(&yc[a1][r]);
            float4 vc = *reinterpret_cast<const float4*>(&yc[a2][r]);
            float4 wa = *reinterpret_cast<const float4*>(&yc[b0][r]);
            float4 wb = *reinterpret_cast<const float4*>(&yc[b1][r]);
            float4 wc = *reinterpret_cast<const float4*>(&yc[b2][r]);
            // (row*454 + j0) is even -> float2-aligned; row stride = 227 float2
            float2* o = reinterpret_cast<float2*>(
                out + (size_t)(row0 + r) * NEXP + j0);
            o[0 * (NEXP / 2)] = {va.x * vb.x * vc.x * sc.x + sh.x,
                                 wa.x * wb.x * wc.x * sc.y + sh.y};
            o[1 * (NEXP / 2)] = {va.y * vb.y * vc.y * sc.x + sh.x,
                                 wa.y * wb.y * wc.y * sc.y + sh.y};
            o[2 * (NEXP / 2)] = {va.z * vb.z * vc.z * sc.x + sh.x,
                                 wa.z * wb.z * wc.z * sc.y + sh.y};
            o[3 * (NEXP / 2)] = {va.w * vb.w * vc.w * sc.x + sh.x,
                                 wa.w * wb.w * wc.w * sc.y + sh.y};
        }
    }
}

extern "C" void kernel_launch(void* const* d_in, const int* in_sizes, int n_in,
                              void* d_out, int out_size, void* d_ws, size_t ws_size,
                              hipStream_t stream) {
    const float* x  = (const float*)d_in[0];
    const float* bw = (const float*)d_in[1];
    const float* bb = (const float*)d_in[2];
    float* out  = (float*)d_out;
    float* part = (float*)d_ws;                    // SBLK*908 floats = 3.7 MB
    float* ss   = part + (size_t)SBLK * PARTW;     // 908 floats scale/shift

    stats_kernel<<<SBLK, 256, 0, stream>>>(x, part);
    finalize_kernel<<<(NEXP + FIN_FPB - 1) / FIN_FPB, 256, 0, stream>>>(part, bw, bb, ss);
    write_kernel<<<NROWS / WROWS, 256, 0, stream>>>(x, ss, out);
}

// Round 13
// 41.184 us; speedup vs baseline: 1.2602x; 1.2602x over previous
//
#include <hip/hip_runtime.h>

#define NF 13          // y = [1, x1..x12]
#define NEXP 454       // unique monomials
#define NROWS 65536
#define BN_EPS 1e-5f
#define SBLK 512               // stats blocks (2/CU)
#define SROWS (NROWS / SBLK)   // 128 rows per stats block
#define PARTW 908              // per-block partial row: [454 sums | 454 sumsqs]
#define SPAD (SROWS + 4)       // padded column stride: 132 words, 16B-aligned
#define WROWS 32               // rows per write block (2048 blocks, 8/CU)
#define WPAD (WROWS + 4)       // 36 words
#define FIN_FPB 8              // features per finalize block -> 57 blocks
#define FIN_SL 32              // slices per feature

// Decode feature index j (0..453) -> nondecreasing triple (i0<=i1<=i2),
// lexicographic order over (i0,i1,i2), skipping (0,0,0).
__device__ __forceinline__ void decode_triple(int j, int& i0, int& i1, int& i2) {
    int g = j + 1;
    i0 = 0;
    for (;;) {
        int m = NF - i0;
        int c = m * (m + 1) / 2;
        if (g < c) break;
        g -= c; ++i0;
    }
    i1 = i0;
    for (;;) {
        int m = NF - i1;
        if (g < m) break;
        g -= m; ++i1;
    }
    i2 = i1 + g;
}

// ---------------- Pass 1: per-block partial sum / sumsq (no atomics) --------
// R9 version byte-for-byte (session best; every rewrite regressed).
__global__ __launch_bounds__(256) void stats_kernel(const float* __restrict__ x,
                                                    float* __restrict__ part) {
    __shared__ float yc[NF][SPAD];
    const int tid = threadIdx.x;
    const int row0 = blockIdx.x * SROWS;

    for (int idx = tid; idx < SROWS * 12; idx += 256) {
        int r = idx / 12, c = idx - r * 12;
        yc[c + 1][r] = x[(size_t)row0 * 12 + idx];
    }
    for (int r = tid; r < SROWS; r += 256) yc[0][r] = 1.0f;
    __syncthreads();

    const int j0 = tid;
    const int j1 = tid + 256;
    const bool has1 = (j1 < NEXP);
    int a0, a1, a2, b0 = 0, b1 = 0, b2 = 0;
    decode_triple(j0, a0, a1, a2);
    if (has1) decode_triple(j1, b0, b1, b2);

    float s0 = 0.f, q0 = 0.f, s1 = 0.f, q1 = 0.f;
    for (int r = 0; r < SROWS; r += 4) {
        float4 va = *reinterpret_cast<const float4*>(&yc[a0][r]);
        float4 vb = *reinterpret_cast<const float4*>(&yc[a1][r]);
        float4 vc = *reinterpret_cast<const float4*>(&yc[a2][r]);
        float f;
        f = va.x * vb.x * vc.x; s0 += f; q0 += f * f;
        f = va.y * vb.y * vc.y; s0 += f; q0 += f * f;
        f = va.z * vb.z * vc.z; s0 += f; q0 += f * f;
        f = va.w * vb.w * vc.w; s0 += f; q0 += f * f;
        if (has1) {
            float4 wa = *reinterpret_cast<const float4*>(&yc[b0][r]);
            float4 wb = *reinterpret_cast<const float4*>(&yc[b1][r]);
            float4 wc = *reinterpret_cast<const float4*>(&yc[b2][r]);
            f = wa.x * wb.x * wc.x; s1 += f; q1 += f * f;
            f = wa.y * wb.y * wc.y; s1 += f; q1 += f * f;
            f = wa.z * wb.z * wc.z; s1 += f; q1 += f * f;
            f = wa.w * wb.w * wc.w; s1 += f; q1 += f * f;
        }
    }
    float* p = part + (size_t)blockIdx.x * PARTW;
    p[j0] = s0;
    p[NEXP + j0] = q0;
    if (has1) {
        p[j1] = s1;
        p[NEXP + j1] = q1;
    }
}

// ---------------- Pass 2: reduce partials, fold BN into scale/shift ---------
// Parallelized: 57 blocks x (8 features x 32 slices); 16 loads/thread
// (was 15 blocks x 64 loads/thread -> few-CU latency-bound tail).
__global__ __launch_bounds__(256) void finalize_kernel(const float* __restrict__ part,
                                                       const float* __restrict__ w,
                                                       const float* __restrict__ b,
                                                       float* __restrict__ ss) {
    __shared__ float reds[FIN_SL][FIN_FPB];
    __shared__ float redq[FIN_SL][FIN_FPB];
    const int fl = threadIdx.x & (FIN_FPB - 1);
    const int k  = threadIdx.x >> 3;              // slice 0..31
    const int f  = blockIdx.x * FIN_FPB + fl;
    float s = 0.f, q = 0.f;
    if (f < NEXP) {
        #pragma unroll 4
        for (int i = 0; i < SBLK / FIN_SL; ++i) {     // 16 part-rows per slice
            const float* p = part + (size_t)(k * (SBLK / FIN_SL) + i) * PARTW;
            s += p[f];
            q += p[NEXP + f];
        }
    }
    reds[k][fl] = s;
    redq[k][fl] = q;
    __syncthreads();
    if (threadIdx.x < FIN_FPB && f < NEXP) {
        float ts = 0.f, tq = 0.f;
        #pragma unroll
        for (int kk = 0; kk < FIN_SL; ++kk) { ts += reds[kk][fl]; tq += redq[kk][fl]; }
        const float inv_n = 1.0f / (float)NROWS;
        float mean = ts * inv_n;
        float var  = tq * inv_n - mean * mean;
        float scale = rsqrtf(var + BN_EPS) * w[f];
        ss[f] = scale;
        ss[NEXP + f] = b[f] - mean * scale;
    }
}

// ---------------- Pass 3: recompute feats, apply affine, store --------------
// Thread t<227 owns FLAT features (2t, 2t+1): always-even index -> aligned
// float2 (dwordx2) stores, 512B contiguous per wave-instruction.
__global__ __launch_bounds__(256) void write_kernel(const float* __restrict__ x,
                                                    const float* __restrict__ ss,
                                                    float* __restrict__ out) {
    __shared__ float yc[NF][WPAD];
    const int tid = threadIdx.x;
    const int row0 = blockIdx.x * WROWS;

    for (int idx = tid; idx < WROWS * 12; idx += 256) {
        int r = idx / 12, c = idx - r * 12;
        yc[c + 1][r] = x[(size_t)row0 * 12 + idx];
    }
    for (int r = tid; r < WROWS; r += 256) yc[0][r] = 1.0f;

    const bool act = tid < NEXP / 2;     // 227 active threads
    const int j0 = 2 * tid;
    int a0 = 0, a1 = 0, a2 = 0, b0 = 0, b1 = 0, b2 = 0;
    float2 sc = {0.f, 0.f}, sh = {0.f, 0.f};
    if (act) {
        decode_triple(j0, a0, a1, a2);
        decode_triple(j0 + 1, b0, b1, b2);
        sc = *reinterpret_cast<const float2*>(&ss[j0]);          // even idx
        sh = *reinterpret_cast<const float2*>(&ss[NEXP + j0]);   // even idx
    }
    __syncthreads();

    if (act) {
        for (int r = 0; r < WROWS; r += 4) {
            float4 va = *reinterpret_cast<const float4*>(&yc[a0][r]);
            float4 vb = *reinterpret_cast<const float4*>(&yc[a1][r]);
            float4 vc = *reinterpret_cast<const float4*>(&yc[a2][r]);
            float4 wa = *reinterpret_cast<const float4*>(&yc[b0][r]);
            float4 wb = *reinterpret_cast<const float4*>(&yc[b1][r]);
            float4 wc = *reinterpret_cast<const float4*>(&yc[b2][r]);
            // (row*454 + j0) is even -> float2-aligned; row stride = 227 float2
            float2* o = reinterpret_cast<float2*>(
                out + (size_t)(row0 + r) * NEXP + j0);
            o[0 * (NEXP / 2)] = {va.x * vb.x * vc.x * sc.x + sh.x,
                                 wa.x * wb.x * wc.x * sc.y + sh.y};
            o[1 * (NEXP / 2)] = {va.y * vb.y * vc.y * sc.x + sh.x,
                                 wa.y * wb.y * wc.y * sc.y + sh.y};
            o[2 * (NEXP / 2)] = {va.z * vb.z * vc.z * sc.x + sh.x,
                                 wa.z * wb.z * wc.z * sc.y + sh.y};
            o[3 * (NEXP / 2)] = {va.w * vb.w * vc.w * sc.x + sh.x,
                                 wa.w * wb.w * wc.w * sc.y + sh.y};
        }
    }
}

extern "C" void kernel_launch(void* const* d_in, const int* in_sizes, int n_in,
                              void* d_out, int out_size, void* d_ws, size_t ws_size,
                              hipStream_t stream) {
    const float* x  = (const float*)d_in[0];
    const float* bw = (const float*)d_in[1];
    const float* bb = (const float*)d_in[2];
    float* out  = (float*)d_out;
    float* part = (float*)d_ws;                    // SBLK*908 floats = 1.86 MB
    float* ss   = part + (size_t)SBLK * PARTW;     // 908 floats scale/shift

    stats_kernel<<<SBLK, 256, 0, stream>>>(x, part);
    finalize_kernel<<<(NEXP + FIN_FPB - 1) / FIN_FPB, 256, 0, stream>>>(part, bw, bb, ss);
    write_kernel<<<NROWS / WROWS, 256, 0, stream>>>(x, ss, out);
}

// Round 14
// 38.400 us; speedup vs baseline: 1.3515x; 1.0725x over previous
//
#include <hip/hip_runtime.h>

#define NF 13          // y = [1, x1..x12]
#define NEXP 454       // unique monomials
#define NROWS 65536
#define BN_EPS 1e-5f
#define SBLK 512               // stats blocks (2/CU, now 512 threads each)
#define SROWS (NROWS / SBLK)   // 128 rows per stats block
#define PARTW 908              // per-block partial row: [454 sums | 454 sumsqs]
#define SPAD (SROWS + 4)       // padded column stride: 132 words, 16B-aligned
#define WROWS 32               // rows per write block (2048 blocks, 8/CU)
#define WPAD (WROWS + 4)       // 36 words
#define FIN_FPB 8              // features per finalize block -> 57 blocks
#define FIN_SL 32              // slices per feature

// Decode feature index j (0..453) -> nondecreasing triple (i0<=i1<=i2),
// lexicographic order over (i0,i1,i2), skipping (0,0,0).
__device__ __forceinline__ void decode_triple(int j, int& i0, int& i1, int& i2) {
    int g = j + 1;
    i0 = 0;
    for (;;) {
        int m = NF - i0;
        int c = m * (m + 1) / 2;
        if (g < c) break;
        g -= c; ++i0;
    }
    i1 = i0;
    for (;;) {
        int m = NF - i1;
        if (g < m) break;
        g -= m; ++i1;
    }
    i2 = i1 + g;
}

// ---------------- Pass 1: per-block partial sum / sumsq (no atomics) --------
// R13 structure, 512 threads/block: ONE feature per thread (no j1 path),
// 16 waves/CU to hide staging + ds_read latency. Per-CU work invariant.
__global__ __launch_bounds__(512) void stats_kernel(const float* __restrict__ x,
                                                    float* __restrict__ part) {
    __shared__ float yc[NF][SPAD];
    const int tid = threadIdx.x;
    const int row0 = blockIdx.x * SROWS;

    for (int idx = tid; idx < SROWS * 12; idx += 512) {
        int r = idx / 12, c = idx - r * 12;
        yc[c + 1][r] = x[(size_t)row0 * 12 + idx];
    }
    for (int r = tid; r < SROWS; r += 512) yc[0][r] = 1.0f;
    __syncthreads();

    if (tid < NEXP) {
        int a0, a1, a2;
        decode_triple(tid, a0, a1, a2);

        float s0 = 0.f, q0 = 0.f;
        for (int r = 0; r < SROWS; r += 4) {
            float4 va = *reinterpret_cast<const float4*>(&yc[a0][r]);
            float4 vb = *reinterpret_cast<const float4*>(&yc[a1][r]);
            float4 vc = *reinterpret_cast<const float4*>(&yc[a2][r]);
            float f;
            f = va.x * vb.x * vc.x; s0 += f; q0 += f * f;
            f = va.y * vb.y * vc.y; s0 += f; q0 += f * f;
            f = va.z * vb.z * vc.z; s0 += f; q0 += f * f;
            f = va.w * vb.w * vc.w; s0 += f; q0 += f * f;
        }
        float* p = part + (size_t)blockIdx.x * PARTW;
        p[tid] = s0;
        p[NEXP + tid] = q0;
    }
}

// ---------------- Pass 2: reduce partials, fold BN into scale/shift ---------
// (R13 version byte-for-byte: 57 blocks x (8 features x 32 slices).)
__global__ __launch_bounds__(256) void finalize_kernel(const float* __restrict__ part,
                                                       const float* __restrict__ w,
                                                       const float* __restrict__ b,
                                                       float* __restrict__ ss) {
    __shared__ float reds[FIN_SL][FIN_FPB];
    __shared__ float redq[FIN_SL][FIN_FPB];
    const int fl = threadIdx.x & (FIN_FPB - 1);
    const int k  = threadIdx.x >> 3;              // slice 0..31
    const int f  = blockIdx.x * FIN_FPB + fl;
    float s = 0.f, q = 0.f;
    if (f < NEXP) {
        #pragma unroll 4
        for (int i = 0; i < SBLK / FIN_SL; ++i) {     // 16 part-rows per slice
            const float* p = part + (size_t)(k * (SBLK / FIN_SL) + i) * PARTW;
            s += p[f];
            q += p[NEXP + f];
        }
    }
    reds[k][fl] = s;
    redq[k][fl] = q;
    __syncthreads();
    if (threadIdx.x < FIN_FPB && f < NEXP) {
        float ts = 0.f, tq = 0.f;
        #pragma unroll
        for (int kk = 0; kk < FIN_SL; ++kk) { ts += reds[kk][fl]; tq += redq[kk][fl]; }
        const float inv_n = 1.0f / (float)NROWS;
        float mean = ts * inv_n;
        float var  = tq * inv_n - mean * mean;
        float scale = rsqrtf(var + BN_EPS) * w[f];
        ss[f] = scale;
        ss[NEXP + f] = b[f] - mean * scale;
    }
}

// ---------------- Pass 3: recompute feats, apply affine, store --------------
// (R13 version byte-for-byte.) Thread t<227 owns FLAT features (2t, 2t+1):
// always-even index -> aligned float2 (dwordx2) stores.
__global__ __launch_bounds__(256) void write_kernel(const float* __restrict__ x,
                                                    const float* __restrict__ ss,
                                                    float* __restrict__ out) {
    __shared__ float yc[NF][WPAD];
    const int tid = threadIdx.x;
    const int row0 = blockIdx.x * WROWS;

    for (int idx = tid; idx < WROWS * 12; idx += 256) {
        int r = idx / 12, c = idx - r * 12;
        yc[c + 1][r] = x[(size_t)row0 * 12 + idx];
    }
    for (int r = tid; r < WROWS; r += 256) yc[0][r] = 1.0f;

    const bool act = tid < NEXP / 2;     // 227 active threads
    const int j0 = 2 * tid;
    int a0 = 0, a1 = 0, a2 = 0, b0 = 0, b1 = 0, b2 = 0;
    float2 sc = {0.f, 0.f}, sh = {0.f, 0.f};
    if (act) {
        decode_triple(j0, a0, a1, a2);
        decode_triple(j0 + 1, b0, b1, b2);
        sc = *reinterpret_cast<const float2*>(&ss[j0]);          // even idx
        sh = *reinterpret_cast<const float2*>(&ss[NEXP + j0]);   // even idx
    }
    __syncthreads();

    if (act) {
        for (int r = 0; r < WROWS; r += 4) {
            float4 va = *reinterpret_cast<const float4*>(&yc[a0][r]);
            float4 vb = *reinterpret_cast<const float4*>(&yc[a1][r]);
            float4 vc = *reinterpret_cast<const float4*>(&yc[a2][r]);
            float4 wa = *reinterpret_cast<const float4*>(&yc[b0][r]);
            float4 wb = *reinterpret_cast<const float4*>(&yc[b1][r]);
            float4 wc = *reinterpret_cast<const float4*>(&yc[b2][r]);
            // (row*454 + j0) is even -> float2-aligned; row stride = 227 float2
            float2* o = reinterpret_cast<float2*>(
                out + (size_t)(row0 + r) * NEXP + j0);
            o[0 * (NEXP / 2)] = {va.x * vb.x * vc.x * sc.x + sh.x,
                                 wa.x * wb.x * wc.x * sc.y + sh.y};
            o[1 * (NEXP / 2)] = {va.y * vb.y * vc.y * sc.x + sh.x,
                                 wa.y * wb.y * wc.y * sc.y + sh.y};
            o[2 * (NEXP / 2)] = {va.z * vb.z * vc.z * sc.x + sh.x,
                                 wa.z * wb.z * wc.z * sc.y + sh.y};
            o[3 * (NEXP / 2)] = {va.w * vb.w * vc.w * sc.x + sh.x,
                                 wa.w * wb.w * wc.w * sc.y + sh.y};
        }
    }
}

extern "C" void kernel_launch(void* const* d_in, const int* in_sizes, int n_in,
                              void* d_out, int out_size, void* d_ws, size_t ws_size,
                              hipStream_t stream) {
    const float* x  = (const float*)d_in[0];
    const float* bw = (const float*)d_in[1];
    const float* bb = (const float*)d_in[2];
    float* out  = (float*)d_out;
    float* part = (float*)d_ws;                    // SBLK*908 floats = 1.86 MB
    float* ss   = part + (size_t)SBLK * PARTW;     // 908 floats scale/shift

    stats_kernel<<<SBLK, 512, 0, stream>>>(x, part);
    finalize_kernel<<<(NEXP + FIN_FPB - 1) / FIN_FPB, 256, 0, stream>>>(part, bw, bb, ss);
    write_kernel<<<NROWS / WROWS, 256, 0, stream>>>(x, ss, out);
}